// Round 1
// baseline (437.387 us; speedup 1.0000x reference)
//
#include <hip/hip_runtime.h>

// Zero-phase FIR band-pass via bf16 MFMA (banded-Toeplitz formulation).
//
// out[t] = sum_{j=0}^{412} h[j] * xs(t + 206 - j)
// xs(s) = x[s] in range; 2*x[0]-x[-s] left; 2*x[T-1]-x[2T-2-s] right.
//
// MFMA mapping (16x16x32 bf16, D[r][n], t = tb + 16n + r):
//   A_sig[r][k] = h[430 + r - k - 32*sig]   (0 if index outside [0,412]),  sig in [0,14)
//   B_sig[k][n] = xs(tb - 224 + 32*sig + k + 16n)
//   out = sum_sig A_sig * B_sig    (each tap j hits exactly one sig)
//
// R1: persistent per-signal blocks (grid = nsig), double-buffered LDS,
//     register-prefetch of next tile's global loads so HBM latency hides
//     under the MFMA/ds_read phase. A fragments loaded once per signal.

#define T_LEN   30000
#define NTAPS   413
#define BLOCK   256            // 4 waves
#define OUT_BLK 2048           // outputs per tile (8 sub-tiles of 256; 2/wave)
#define BLK_PER_SIG 15         // ceil(30000/2048)
#define NSIG_A  14             // sigma count (448 effective taps >= 413+15)
#define XS_LEN  2480           // staged samples: OUT_BLK - 256 + 688
#define NCHUNK  310            // XS_LEN / 8 (16B bf16 chunks)
#define LDS_CHUNKS 348         // NCHUNK + NCHUNK/8 padding (16B pad per 128B)

typedef __bf16 bf16x8 __attribute__((ext_vector_type(8)));
typedef float  f32x4  __attribute__((ext_vector_type(4)));

union Chunk {
    uint4 v;
    unsigned short us[8];
    bf16x8 f;
};

__device__ __forceinline__ unsigned short f32_to_bf16_rne(float f) {
    unsigned u = __float_as_uint(f);
    unsigned r = u + 0x7FFFu + ((u >> 16) & 1u);
    return (unsigned short)(r >> 16);
}

// phys index of logical 16B chunk u (pad 1 chunk per 8 -> breaks even-stride conflicts)
__device__ __forceinline__ int cpad(int u) { return u + (u >> 3); }

__global__ void prep_A_kernel(const float* __restrict__ h, uint4* __restrict__ wsA) {
    int i = blockIdx.x * blockDim.x + threadIdx.x;   // 0 .. 14*64-1
    if (i >= NSIG_A * 64) return;
    int sig = i >> 6, lane = i & 63;
    int r = lane & 15, q = lane >> 4;
    Chunk c;
    #pragma unroll
    for (int j = 0; j < 8; ++j) {
        int idx = 430 + r - 8 * q - j - 32 * sig;
        float v = (idx >= 0 && idx < NTAPS) ? h[idx] : 0.0f;
        c.us[j] = f32_to_bf16_rne(v);
    }
    wsA[i] = c.v;
}

// raw (unconverted) load of the 8 floats feeding chunk u with g0 = first index
__device__ __forceinline__ void chunk_load(const float* __restrict__ xp, int g0,
                                           float r[8]) {
    if (g0 >= 0 && g0 + 8 <= T_LEN) {
        float4 a = *reinterpret_cast<const float4*>(xp + g0);
        float4 b = *reinterpret_cast<const float4*>(xp + g0 + 4);
        r[0] = a.x; r[1] = a.y; r[2] = a.z; r[3] = a.w;
        r[4] = b.x; r[5] = b.y; r[6] = b.z; r[7] = b.w;
    } else {
        #pragma unroll
        for (int j = 0; j < 8; ++j) {
            int g = g0 + j;
            int idx = (g < 0) ? -g : ((g >= T_LEN) ? (2 * T_LEN - 2 - g) : g);
            r[j] = xp[idx];
        }
    }
}

// convert (+reflect fixup on edge chunks) and write chunk u into an LDS buffer
__device__ __forceinline__ void chunk_store(uint4* __restrict__ buf, int u, int g0,
                                            const float r[8], float x0, float xl) {
    Chunk c;
    if (g0 >= 0 && g0 + 8 <= T_LEN) {
        #pragma unroll
        for (int j = 0; j < 8; ++j) c.us[j] = f32_to_bf16_rne(r[j]);
    } else {
        #pragma unroll
        for (int j = 0; j < 8; ++j) {
            int g = g0 + j;
            float v = r[j];
            if (g < 0)           v = 2.0f * x0 - v;
            else if (g >= T_LEN) v = 2.0f * xl - v;
            c.us[j] = f32_to_bf16_rne(v);
        }
    }
    buf[cpad(u)] = c.v;
}

__global__ __launch_bounds__(BLOCK, 4) void fir_mfma_kernel(
    const float* __restrict__ x, const uint4* __restrict__ wsA,
    float* __restrict__ out)
{
    __shared__ uint4 lds[2][LDS_CHUNKS];   // double-buffered staged signal

    const int tid = threadIdx.x;
    const int sig_id = blockIdx.x;
    const float* xp = x   + (size_t)sig_id * T_LEN;
    float*       op = out + (size_t)sig_id * T_LEN;

    const int lane = tid & 63;
    const int wv   = tid >> 6;

    // ---- load A fragments once per signal (L2-hot after first blocks) ----
    bf16x8 A[NSIG_A];
    #pragma unroll
    for (int s = 0; s < NSIG_A; ++s) {
        Chunk c; c.v = wsA[s * 64 + lane];
        A[s] = c.f;
    }

    const float x0 = xp[0], xl = xp[T_LEN - 1];

    // each thread owns chunk tid, plus chunk tid+256 for tid < 54
    const bool has2 = (tid < NCHUNK - 256);
    float r0[8], r1[8];

    // ---- prologue: stage tile 0 into lds[0] ----
    {
        int g0 = -224 + 8 * tid;
        chunk_load(xp, g0, r0);
        if (has2) chunk_load(xp, g0 + 8 * 256, r1);
        chunk_store(&lds[0][0], tid, g0, r0, x0, xl);
        if (has2) chunk_store(&lds[0][0], tid + 256, g0 + 8 * 256, r1, x0, xl);
    }
    __syncthreads();

    const int n = lane & 15, q = lane >> 4;
    const int base_u = 64 * wv + 2 * n + q;

    for (int blk = 0; blk < BLK_PER_SIG; ++blk) {
        const int cur = blk & 1;
        const int t0  = blk * OUT_BLK;
        const bool pf = (blk + 1 < BLK_PER_SIG);
        const int ng0 = (blk + 1) * OUT_BLK - 224 + 8 * tid;

        // ---- issue next tile's global loads (in flight across the compute) ----
        if (pf) {
            chunk_load(xp, ng0, r0);
            if (has2) chunk_load(xp, ng0 + 8 * 256, r1);
        }

        // ---- compute current tile from lds[cur]: wave wv owns sub-tiles
        //      mt = 2*wv, 2*wv+1; fragments shared along phi. ----
        const uint4* __restrict__ cb = &lds[cur][0];
        f32x4 acc0 = {0.f, 0.f, 0.f, 0.f};
        f32x4 acc1 = {0.f, 0.f, 0.f, 0.f};
        #pragma unroll
        for (int phi = 0; phi < NSIG_A + 8; ++phi) {   // 22
            Chunk c; c.v = cb[cpad(base_u + 4 * phi)];
            bf16x8 B = c.f;
            if (phi < NSIG_A)
                acc0 = __builtin_amdgcn_mfma_f32_16x16x32_bf16(A[phi], B, acc0, 0, 0, 0);
            if (phi >= 8)
                acc1 = __builtin_amdgcn_mfma_f32_16x16x32_bf16(A[phi - 8], B, acc1, 0, 0, 0);
        }

        // ---- store: C/D layout col=lane&15 (n), row=(lane>>4)*4+v.
        // t = t0 + 256*mt + 16n + 4q + v -> one float4 per lane, coalesced. ----
        const int tA = t0 + 256 * (2 * wv) + 16 * n + 4 * q;
        if (tA < T_LEN)
            *reinterpret_cast<float4*>(op + tA) =
                make_float4(acc0.x, acc0.y, acc0.z, acc0.w);
        const int tB = tA + 256;
        if (tB < T_LEN)
            *reinterpret_cast<float4*>(op + tB) =
                make_float4(acc1.x, acc1.y, acc1.z, acc1.w);

        // ---- convert + write next tile into the other buffer ----
        if (pf) {
            uint4* __restrict__ nb = &lds[cur ^ 1][0];
            chunk_store(nb, tid, ng0, r0, x0, xl);
            if (has2) chunk_store(nb, tid + 256, ng0 + 8 * 256, r1, x0, xl);
        }
        __syncthreads();
    }
}

extern "C" void kernel_launch(void* const* d_in, const int* in_sizes, int n_in,
                              void* d_out, int out_size, void* d_ws, size_t ws_size,
                              hipStream_t stream) {
    const float* x = (const float*)d_in[0];
    const float* h = (const float*)d_in[1];
    float* out = (float*)d_out;
    uint4* wsA = (uint4*)d_ws;                       // 14*64*16 = 14336 B
    const int nsig = in_sizes[0] / T_LEN;            // 2048

    prep_A_kernel<<<dim3(4), dim3(BLOCK), 0, stream>>>(h, wsA);
    fir_mfma_kernel<<<dim3(nsig), dim3(BLOCK), 0, stream>>>(x, wsA, out);
}